// Round 18
// baseline (5004.884 us; speedup 1.0000x reference)
//
#include <hip/hip_runtime.h>
#include <cmath>

#define AGENT __HIP_MEMORY_SCOPE_AGENT

// Problem constants
// B=4, S=512, I=H=768, 3H=2304, E=8, K=2, L=2, tokens=2048, assignments=4096

typedef __attribute__((ext_vector_type(8))) short short8;
typedef __attribute__((ext_vector_type(4))) float f32x4;

// ---------------- reset: NaN-fill hstep (COHERENT), zero zbuf, counts ----
__global__ __launch_bounds__(256)
void reset_kernel(float* __restrict__ hstep, float* __restrict__ zbuf,
                  int* __restrict__ counts) {
  int i = blockIdx.x * 256 + threadIdx.x;
  if (i < 786432) {   // 2 layers * 512 * 3072 floats / 4
    float qn = __uint_as_float(0x7FC00000u);
    float* p = hstep + (size_t)i * 4;
    __hip_atomic_store(p + 0, qn, __ATOMIC_RELAXED, AGENT);
    __hip_atomic_store(p + 1, qn, __ATOMIC_RELAXED, AGENT);
    __hip_atomic_store(p + 2, qn, __ATOMIC_RELAXED, AGENT);
    __hip_atomic_store(p + 3, qn, __ATOMIC_RELAXED, AGENT);
  }
  if (i < 768) {      // zbuf [4][768] zeros
    float* p = zbuf + (size_t)i * 4;
    __hip_atomic_store(p + 0, 0.f, __ATOMIC_RELAXED, AGENT);
    __hip_atomic_store(p + 1, 0.f, __ATOMIC_RELAXED, AGENT);
    __hip_atomic_store(p + 2, 0.f, __ATOMIC_RELAXED, AGENT);
    __hip_atomic_store(p + 3, 0.f, __ATOMIC_RELAXED, AGENT);
  }
  if (i < 16) counts[i] = 0;
}

// ---------------- split fp32 -> bf16 hi/lo planes ----------------
__global__ __launch_bounds__(256)
void split_kernel(const float* __restrict__ in, short* __restrict__ hi,
                  short* __restrict__ lo, int n4) {
  int i = blockIdx.x * 256 + threadIdx.x;
  if (i >= n4) return;
  float4 v = ((const float4*)in)[i];
  unsigned ua = __float_as_uint(v.x), ub = __float_as_uint(v.y);
  unsigned uc = __float_as_uint(v.z), ud = __float_as_uint(v.w);
  unsigned ha = ua & 0xFFFF0000u, hb = ub & 0xFFFF0000u;
  unsigned hc = uc & 0xFFFF0000u, hd = ud & 0xFFFF0000u;
  unsigned hp0 = (ua >> 16) | hb;
  unsigned hp1 = (uc >> 16) | hd;
  float la = v.x - __uint_as_float(ha), lb = v.y - __uint_as_float(hb);
  float lc = v.z - __uint_as_float(hc), ld = v.w - __uint_as_float(hd);
  unsigned lp0 = (__float_as_uint(la) >> 16) | (__float_as_uint(lb) & 0xFFFF0000u);
  unsigned lp1 = (__float_as_uint(lc) >> 16) | (__float_as_uint(ld) & 0xFFFF0000u);
  ((uint2*)hi)[i] = make_uint2(hp0, hp1);
  ((uint2*)lo)[i] = make_uint2(lp0, lp1);
}

// ---------------- dense fp32 GEMM (proj / gi) ----------------
template<bool GI3>
__global__ __launch_bounds__(256)
void gemm_nt(const float* __restrict__ A, const float* __restrict__ Bw,
             const float* __restrict__ bias, float* __restrict__ C,
             int Kd, int lda, int ldc)
{
  __shared__ float As[16][132];
  __shared__ float Bs[16][132];

  int mbase = blockIdx.y * 128;
  int nbase = blockIdx.x * 128;
  int tid = threadIdx.x;
  int tx = tid & 15, ty = tid >> 4;

  const float* ap[2];
  const float* bp[2];
  int ldst[2];
#pragma unroll
  for (int i = 0; i < 2; ++i) {
    int v = tid + 256 * i;
    int row = v >> 2, kq = v & 3;
    ap[i] = A + (size_t)(mbase + row) * lda + kq * 4;
    bp[i] = Bw + (size_t)(nbase + row) * Kd + kq * 4;
    ldst[i] = kq * 4 * 132 + row;
  }

  float acc[8][8];
#pragma unroll
  for (int i = 0; i < 8; ++i)
#pragma unroll
    for (int j = 0; j < 8; ++j) acc[i][j] = 0.f;

  for (int kb = 0; kb < Kd; kb += 16) {
    float4 av[2], bv[2];
#pragma unroll
    for (int i = 0; i < 2; ++i) {
      av[i] = *(const float4*)(ap[i] + kb);
      bv[i] = *(const float4*)(bp[i] + kb);
    }
    if (kb) __syncthreads();
#pragma unroll
    for (int i = 0; i < 2; ++i) {
      float* ad = &As[0][0] + ldst[i];
      ad[0] = av[i].x; ad[132] = av[i].y; ad[264] = av[i].z; ad[396] = av[i].w;
      float* bd = &Bs[0][0] + ldst[i];
      bd[0] = bv[i].x; bd[132] = bv[i].y; bd[264] = bv[i].z; bd[396] = bv[i].w;
    }
    __syncthreads();
#pragma unroll
    for (int kk = 0; kk < 16; ++kk) {
      float a[8], b[8];
      *(float4*)&a[0] = *(const float4*)&As[kk][ty * 4];
      *(float4*)&a[4] = *(const float4*)&As[kk][ty * 4 + 64];
      *(float4*)&b[0] = *(const float4*)&Bs[kk][tx * 4];
      *(float4*)&b[4] = *(const float4*)&Bs[kk][tx * 4 + 64];
#pragma unroll
      for (int i = 0; i < 8; ++i)
#pragma unroll
        for (int j = 0; j < 8; ++j)
          acc[i][j] = fmaf(a[i], b[j], acc[i][j]);
    }
  }

#pragma unroll
  for (int i = 0; i < 8; ++i) {
    int lrow = ty * 4 + (i & 3) + ((i >> 2) << 6);
    int grow = mbase + lrow;
#pragma unroll
    for (int q = 0; q < 2; ++q) {
      int col = nbase + tx * 4 + (q << 6);
      float4 bb = *(const float4*)&bias[col];
      float4 st = make_float4(acc[i][q * 4 + 0] + bb.x, acc[i][q * 4 + 1] + bb.y,
                              acc[i][q * 4 + 2] + bb.z, acc[i][q * 4 + 3] + bb.w);
      if constexpr (GI3) {
        int t = grow & 511, bb2 = grow >> 9;
        int gate = col / 768, jj = col - gate * 768;   // jj%4==0
        int wv = jj >> 2;
        float* dst = C + ((((size_t)t * 4 + bb2) * 192 + wv) * 12 + gate * 4);
        *(float4*)dst = st;
      } else {
        *(float4*)&C[(size_t)grow * ldc + col] = st;
      }
    }
  }
}

// ---------------- split-bf16 MFMA expert GEMM (round-14 proven) ----------
template<bool SHIFT, bool RELU, bool GATE, bool OUTSPLIT>
__global__ __launch_bounds__(256)
void gemm_mfma(const short* __restrict__ Ah_g, const short* __restrict__ Al_g,
               const float* __restrict__ Bw, const float* __restrict__ bias,
               float* __restrict__ C, short* __restrict__ Ch,
               short* __restrict__ Cl, int Kd, int lda, int ldc,
               const int* __restrict__ list, const int* __restrict__ count,
               const float* __restrict__ gates, long wstride, int bstride)
{
  __shared__ __align__(16) short Ah[128][40];
  __shared__ __align__(16) short Al[128][40];
  __shared__ __align__(16) short Bh[128][40];
  __shared__ __align__(16) short Bl[128][40];
  __shared__ int rowlist[128];

  int e = blockIdx.z;
  int cnt = count[e];
  int mbase = blockIdx.y * 128;
  if (mbase >= cnt) return;
  int nbase = blockIdx.x * 128;
  const float* Bp = Bw + (size_t)e * (size_t)wstride;
  const float* biasp = bias + (size_t)e * (size_t)bstride;

  int tid = threadIdx.x;
  if (tid < 128) {
    int r = mbase + tid;
    rowlist[tid] = list[e * 4096 + (r < cnt ? r : cnt - 1)];
  }
  __syncthreads();

  int arow = tid >> 1, ahalf = tid & 1;
  int aidx0 = rowlist[arow];
  int sr = SHIFT ? (aidx0 >> 1) : aidx0;
  const short* aph = Ah_g + (size_t)sr * lda + ahalf * 16;
  const short* apl = Al_g + (size_t)sr * lda + ahalf * 16;
  const float* bp = Bp + (size_t)(nbase + arow) * Kd + ahalf * 16;

  int wave = tid >> 6, lane = tid & 63;
  int wr = (wave >> 1) * 64, wc = (wave & 1) * 64;
  int fr = lane & 15, fo = (lane >> 4) * 8;

  f32x4 acc[4][4];
#pragma unroll
  for (int i = 0; i < 4; ++i)
#pragma unroll
    for (int j = 0; j < 4; ++j) acc[i][j] = f32x4{0.f, 0.f, 0.f, 0.f};

  for (int kb = 0; kb < Kd; kb += 32) {
    uint4 a_h0 = *(const uint4*)(aph + kb);
    uint4 a_h1 = *(const uint4*)(aph + kb + 8);
    uint4 a_l0 = *(const uint4*)(apl + kb);
    uint4 a_l1 = *(const uint4*)(apl + kb + 8);
    float4 b0 = *(const float4*)(bp + kb);
    float4 b1 = *(const float4*)(bp + kb + 4);
    float4 b2 = *(const float4*)(bp + kb + 8);
    float4 b3 = *(const float4*)(bp + kb + 12);
    if (kb) __syncthreads();
    *(uint4*)&Ah[arow][ahalf * 16] = a_h0;
    *(uint4*)&Ah[arow][ahalf * 16 + 8] = a_h1;
    *(uint4*)&Al[arow][ahalf * 16] = a_l0;
    *(uint4*)&Al[arow][ahalf * 16 + 8] = a_l1;
    unsigned hp[8], lp[8];
    const float4 bbv[4] = {b0, b1, b2, b3};
#pragma unroll
    for (int q = 0; q < 4; ++q) {
      unsigned ua = __float_as_uint(bbv[q].x), ub = __float_as_uint(bbv[q].y);
      unsigned uc = __float_as_uint(bbv[q].z), ud = __float_as_uint(bbv[q].w);
      unsigned ha = ua & 0xFFFF0000u, hb = ub & 0xFFFF0000u;
      unsigned hc = uc & 0xFFFF0000u, hd = ud & 0xFFFF0000u;
      hp[q * 2] = (ua >> 16) | hb;
      hp[q * 2 + 1] = (uc >> 16) | hd;
      float la = bbv[q].x - __uint_as_float(ha);
      float lb = bbv[q].y - __uint_as_float(hb);
      float lc = bbv[q].z - __uint_as_float(hc);
      float ld = bbv[q].w - __uint_as_float(hd);
      lp[q * 2] = (__float_as_uint(la) >> 16) | (__float_as_uint(lb) & 0xFFFF0000u);
      lp[q * 2 + 1] = (__float_as_uint(lc) >> 16) | (__float_as_uint(ld) & 0xFFFF0000u);
    }
    *(uint4*)&Bh[arow][ahalf * 16] = make_uint4(hp[0], hp[1], hp[2], hp[3]);
    *(uint4*)&Bh[arow][ahalf * 16 + 8] = make_uint4(hp[4], hp[5], hp[6], hp[7]);
    *(uint4*)&Bl[arow][ahalf * 16] = make_uint4(lp[0], lp[1], lp[2], lp[3]);
    *(uint4*)&Bl[arow][ahalf * 16 + 8] = make_uint4(lp[4], lp[5], lp[6], lp[7]);
    __syncthreads();

    short8 fah[4], fal[4], fbh[4], fbl[4];
#pragma unroll
    for (int mt = 0; mt < 4; ++mt) {
      fah[mt] = *(const short8*)&Ah[wr + mt * 16 + fr][fo];
      fal[mt] = *(const short8*)&Al[wr + mt * 16 + fr][fo];
    }
#pragma unroll
    for (int nt = 0; nt < 4; ++nt) {
      fbh[nt] = *(const short8*)&Bh[wc + nt * 16 + fr][fo];
      fbl[nt] = *(const short8*)&Bl[wc + nt * 16 + fr][fo];
    }
#pragma unroll
    for (int mt = 0; mt < 4; ++mt)
#pragma unroll
      for (int nt = 0; nt < 4; ++nt) {
        acc[mt][nt] = __builtin_amdgcn_mfma_f32_16x16x32_bf16(fah[mt], fbh[nt], acc[mt][nt], 0, 0, 0);
        acc[mt][nt] = __builtin_amdgcn_mfma_f32_16x16x32_bf16(fah[mt], fbl[nt], acc[mt][nt], 0, 0, 0);
        acc[mt][nt] = __builtin_amdgcn_mfma_f32_16x16x32_bf16(fal[mt], fbh[nt], acc[mt][nt], 0, 0, 0);
      }
  }

  int crow = (lane >> 4) * 4;
#pragma unroll
  for (int mt = 0; mt < 4; ++mt) {
#pragma unroll
    for (int q = 0; q < 4; ++q) {
      int lrow = wr + mt * 16 + crow + q;
      int grow = mbase + lrow;
      if (grow < cnt) {
        int aidx = rowlist[lrow];
#pragma unroll
        for (int nt = 0; nt < 4; ++nt) {
          int col = nbase + wc + nt * 16 + fr;
          float v = acc[mt][nt][q] + biasp[col];
          if (RELU) v = fmaxf(v, 0.f);
          if (GATE) v *= gates[aidx];
          if (OUTSPLIT) {
            unsigned u = __float_as_uint(v);
            unsigned h = u & 0xFFFF0000u;
            Ch[(size_t)aidx * ldc + col] = (short)(u >> 16);
            float l2 = v - __uint_as_float(h);
            Cl[(size_t)aidx * ldc + col] = (short)(__float_as_uint(l2) >> 16);
          } else {
            C[(size_t)aidx * ldc + col] = v;
          }
        }
      }
    }
  }
}

// ---------------- GRU persistent kernel: NaN-sentinel, low-traffic poll --
// 4 batch groups x 24 WGs. hstep coherent-only (sc0 sc1) everywhere.
// This round: 48 pollers/WG (4 float4s each -> 4x fewer poll packets),
// phase-delayed first sample (skip guaranteed-NaN window), producer packs
// 4 scalar stores into 2x 8B stores (shfl_xor pair pack).
__global__ __launch_bounds__(512, 2)
void gru_kernel(const float* __restrict__ gi3, float* __restrict__ h_seq,
                float* __restrict__ hstep, const float* __restrict__ hprev,
                const float* __restrict__ Whh, const float* __restrict__ bhh)
{
  const int H = 768, S = 512;
  __shared__ float hs[768];
  int wg = blockIdx.x;           // 0..95
  int b = wg / 24;               // batch group 0..3
  int wgi = wg - b * 24;         // 0..23 within group
  int tid = threadIdx.x;         // 0..511
  int wave = tid >> 6;           // 0..7
  int lane = tid & 63;
  int wv = wgi * 8 + wave;       // 0..191: owns cols wv*4..wv*4+3

  float W[4][3][12];
#pragma unroll
  for (int c = 0; c < 4; ++c)
#pragma unroll
    for (int g = 0; g < 3; ++g) {
      const float* wp = Whh + (size_t)(g * H + wv * 4 + c) * H + lane * 4;
      *(float4*)&W[c][g][0] = *(const float4*)(wp);
      *(float4*)&W[c][g][4] = *(const float4*)(wp + 256);
      *(float4*)&W[c][g][8] = *(const float4*)(wp + 512);
    }
  int mycol = wv * 4 + (lane & 3);
  float bh_r = bhh[mycol], bh_z = bhh[H + mycol], bh_n = bhh[2 * H + mycol];

  float h_own = 0.f;
  if (lane < 4)
    h_own = __hip_atomic_load(&hprev[b * H + mycol], __ATOMIC_RELAXED, AGENT);

  for (int tl = 0; tl < S; ++tl) {
    // gi prefetch (plain cached load; overlaps the poll)
    float gv = 0.f;
    if (lane < 12)
      gv = gi3[((((size_t)tl * 4 + b) * 192 + wv) * 12) + lane];

    // ---- acquire h[tl-1][b]: 48 pollers x 4 float4 (64B region each) ----
    float4 a0, a1, a2, a3;
    a0 = a1 = a2 = a3 = make_float4(0.f, 0.f, 0.f, 0.f);
    if (tid < 48) {   // wave 0, lanes 0..47 (wave-uniform-ish, lane-pred)
      const float* src = (tl == 0)
          ? (hprev + b * 768 + tid * 16)
          : (hstep + ((size_t)(tl - 1) * 4 + b) * 768 + tid * 16);
      if (tl == 0) {
        asm volatile("global_load_dwordx4 %0, %1, off sc0 sc1"
                     : "=v"(a0) : "v"(src) : "memory");
        asm volatile("global_load_dwordx4 %0, %1, off sc0 sc1"
                     : "=v"(a1) : "v"(src + 4) : "memory");
        asm volatile("global_load_dwordx4 %0, %1, off sc0 sc1"
                     : "=v"(a2) : "v"(src + 8) : "memory");
        asm volatile("global_load_dwordx4 %0, %1, off sc0 sc1"
                     : "=v"(a3) : "v"(src + 12) : "memory");
        asm volatile("s_waitcnt vmcnt(0)" ::: "memory");
      } else {
        __builtin_amdgcn_s_sleep(10);   // skip guaranteed-miss window
        for (;;) {
          asm volatile("global_load_dwordx4 %0, %1, off sc0 sc1"
                       : "=v"(a0) : "v"(src) : "memory");
          asm volatile("global_load_dwordx4 %0, %1, off sc0 sc1"
                       : "=v"(a1) : "v"(src + 4) : "memory");
          asm volatile("global_load_dwordx4 %0, %1, off sc0 sc1"
                       : "=v"(a2) : "v"(src + 8) : "memory");
          asm volatile("global_load_dwordx4 %0, %1, off sc0 sc1"
                       : "=v"(a3) : "v"(src + 12) : "memory");
          asm volatile("s_waitcnt vmcnt(0)" ::: "memory");
          bool bad = (a0.x != a0.x) | (a0.y != a0.y) | (a0.z != a0.z) | (a0.w != a0.w) |
                     (a1.x != a1.x) | (a1.y != a1.y) | (a1.z != a1.z) | (a1.w != a1.w) |
                     (a2.x != a2.x) | (a2.y != a2.y) | (a2.z != a2.z) | (a2.w != a2.w) |
                     (a3.x != a3.x) | (a3.y != a3.y) | (a3.z != a3.z) | (a3.w != a3.w);
          if (!bad) break;
          __builtin_amdgcn_s_sleep(2);
        }
      }
    }
    __builtin_amdgcn_sched_barrier(0);
    if (tid < 48) {
      *(float4*)&hs[tid * 16]      = a0;
      *(float4*)&hs[tid * 16 + 4]  = a1;
      *(float4*)&hs[tid * 16 + 8]  = a2;
      *(float4*)&hs[tid * 16 + 12] = a3;
    }
    __syncthreads();

    // ---- sharded h_seq write of h[b][tl-1] (plain store, off chain) ----
    // WG wgi owns cols [wgi*32, wgi*32+32) = threads wgi*2, wgi*2+1
    if (tl >= 1 && (tid >> 1) == wgi) {
      float* dst = h_seq + ((size_t)b * S + (tl - 1)) * H + tid * 16;
      *(float4*)(dst)      = a0;
      *(float4*)(dst + 4)  = a1;
      *(float4*)(dst + 8)  = a2;
      *(float4*)(dst + 12) = a3;
    }

    // ---- fragments from LDS ----
    float hseg[12];
    *(float4*)&hseg[0] = *(const float4*)&hs[lane * 4];
    *(float4*)&hseg[4] = *(const float4*)&hs[256 + lane * 4];
    *(float4*)&hseg[8] = *(const float4*)&hs[512 + lane * 4];
    __syncthreads();   // hs safe to overwrite next iteration

    float acc[4][3];
#pragma unroll
    for (int c = 0; c < 4; ++c)
#pragma unroll
      for (int gg = 0; gg < 3; ++gg) {
        float s = 0.f;
#pragma unroll
        for (int i = 0; i < 12; ++i) s = fmaf(W[c][gg][i], hseg[i], s);
        acc[c][gg] = s;
      }
#pragma unroll
    for (int c = 0; c < 4; ++c)
#pragma unroll
      for (int gg = 0; gg < 3; ++gg) {
        float v = acc[c][gg];
#pragma unroll
        for (int m = 32; m >= 1; m >>= 1) v += __shfl_xor(v, m);
        acc[c][gg] = v;
      }

    float gi_r = __shfl(gv, (lane & 3));
    float gi_z = __shfl(gv, 4 + (lane & 3));
    float gi_n = __shfl(gv, 8 + (lane & 3));

    float hn = 0.f;
    if (lane < 4) {
      float ar = acc[0][0], az = acc[0][1], an = acc[0][2];
      if (lane == 1) { ar = acc[1][0]; az = acc[1][1]; an = acc[1][2]; }
      if (lane == 2) { ar = acc[2][0]; az = acc[2][1]; an = acc[2][2]; }
      if (lane == 3) { ar = acc[3][0]; az = acc[3][1]; an = acc[3][2]; }
      float r = 1.f / (1.f + expf(-(gi_r + ar + bh_r)));
      float z = 1.f / (1.f + expf(-(gi_z + az + bh_z)));
      float n = tanhf(gi_n + r * (an + bh_n));
      hn = (1.f - z) * n + z * h_own;
      h_own = hn;
    }
    // pack pairs: lane0 gets lane1's value, lane2 gets lane3's (and vice versa)
    float hn_other = __shfl_xor(hn, 1);
    if ((lane & 1) == 0 && lane < 4) {
      // lane0: (c0,c1) at +wv*4 ; lane2: (c2,c3) at +wv*4+2
      unsigned long long packed =
          ((unsigned long long)__float_as_uint(hn_other) << 32) |
          (unsigned long long)__float_as_uint(hn);
      unsigned long long* dst = (unsigned long long*)
          (hstep + ((size_t)tl * 4 + b) * 768 + wv * 4 + lane);
      __hip_atomic_store(dst, packed, __ATOMIC_RELAXED, AGENT);
    }
  }

  // epilogue: write h[b][S-1] to h_seq from registers
  if (lane < 4)
    h_seq[((size_t)b * S + (S - 1)) * H + mycol] = h_own;
}

// ---------------- router + top-2 + gates + expert lists ----------------
__global__ __launch_bounds__(64)
void router_kernel(const float* __restrict__ h_seq, const float* __restrict__ rW,
                   const float* __restrict__ rb, int* __restrict__ counts,
                   int* __restrict__ lists, float* __restrict__ gates)
{
  int t = blockIdx.x;
  int lane = threadIdx.x;
  const float* hp = h_seq + (size_t)t * 768 + lane * 12;
  float h[12];
  *(float4*)&h[0] = *(const float4*)(hp);
  *(float4*)&h[4] = *(const float4*)(hp + 4);
  *(float4*)&h[8] = *(const float4*)(hp + 8);

  float lg[8];
#pragma unroll
  for (int e = 0; e < 8; ++e) {
    const float* wp = rW + e * 768 + lane * 12;
    float s = 0.f;
#pragma unroll
    for (int i = 0; i < 12; ++i) s = fmaf(h[i], wp[i], s);
#pragma unroll
    for (int m = 32; m >= 1; m >>= 1) s += __shfl_xor(s, m);
    lg[e] = s + rb[e];
  }
  if (lane == 0) {
    float v1 = lg[0]; int e1 = 0;
#pragma unroll
    for (int e = 1; e < 8; ++e) {
      if (lg[e] > v1) { v1 = lg[e]; e1 = e; }
    }
    float v2 = -INFINITY; int es = 0;
#pragma unroll
    for (int e = 0; e < 8; ++e) {
      if (e != e1 && lg[e] > v2) { v2 = lg[e]; es = e; }
    }
    float ed = expf(v2 - v1);
    float g1 = 1.f / (1.f + ed);
    float g2 = ed / (1.f + ed);
    int a0 = t * 2, a1 = t * 2 + 1;
    gates[a0] = g1;
    gates[a1] = g2;
    int p = atomicAdd(&counts[e1], 1);
    lists[e1 * 4096 + p] = a0;
    p = atomicAdd(&counts[es], 1);
    lists[es * 4096 + p] = a1;
  }
}

// ---------------- combine: x_next[t] = ybuf[2t] + ybuf[2t+1] ----------------
__global__ __launch_bounds__(256)
void combine_kernel(const float* __restrict__ ybuf, float* __restrict__ out)
{
  int i = blockIdx.x * 256 + threadIdx.x;
  int fi = i * 4;
  int t = fi / 768;
  int d = fi % 768;
  float4 y0 = *(const float4*)&ybuf[(size_t)(2 * t) * 768 + d];
  float4 y1 = *(const float4*)&ybuf[(size_t)(2 * t + 1) * 768 + d];
  float4 r = make_float4(y0.x + y1.x, y0.y + y1.y, y0.z + y1.z, y0.w + y1.w);
  *(float4*)&out[fi] = r;
}

// ---------------- host ----------------
extern "C" void kernel_launch(void* const* d_in, const int* in_sizes, int n_in,
                              void* d_out, int out_size, void* d_ws, size_t ws_size,
                              hipStream_t stream) {
  (void)in_sizes; (void)n_in; (void)out_size; (void)ws_size;
  const float* x      = (const float*)d_in[0];
  const float* proj_W = (const float*)d_in[1];
  const float* proj_b = (const float*)d_in[2];
  const float* Wih    = (const float*)d_in[3];
  const float* Whh    = (const float*)d_in[4];
  const float* bih    = (const float*)d_in[5];
  const float* bhh    = (const float*)d_in[6];
  const float* rW     = (const float*)d_in[7];
  const float* rb     = (const float*)d_in[8];
  const float* eW1    = (const float*)d_in[9];
  const float* eb1    = (const float*)d_in[10];
  const float* eW2    = (const float*)d_in[11];
  const float* eb2    = (const float*)d_in[12];
  float* out = (float*)d_out;

  // workspace layout
  float* f = (float*)d_ws;
  float* h_in  = f;                    // 1,572,864
  float* gi3   = h_in + 1572864;       // 512*4*192*12 = 4,718,592
  float* h_seq = gi3 + 4718592;        // 1,572,864
  float* x_buf = h_seq + 1572864;      // 1,572,864
  float* ybuf  = x_buf + 1572864;      // 3,145,728
  float* hstep = ybuf + 3145728;       // 2*512*4*768 = 3,145,728
  float* zbuf  = hstep + 3145728;      // 3,072 ([4][768] zeros)
  float* gates = zbuf + 3072;          // 4,096
  short* xh    = (short*)(gates + 4096);  // 1,572,864 shorts
  short* xl    = xh + 1572864;            // 1,572,864 shorts
  short* H1h   = xl + 1572864;            // 12,582,912 shorts
  short* H1l   = H1h + 12582912;          // 12,582,912 shorts
  int* ints    = (int*)(H1l + 12582912);
  int* counts  = ints;                 // 16
  int* lists   = ints + 16;            // 8*4096

  reset_kernel<<<3072, 256, 0, stream>>>(hstep, zbuf, counts);

  for (int l = 0; l < 2; ++l) {
    const float* xin = l ? x_buf : x;
    float* hstepL = hstep + (size_t)l * 1572864;
    const float* hprevL = l ? (hstep + (size_t)511 * 3072) : zbuf;

    dim3 g1(6, 16);
    gemm_nt<false><<<g1, 256, 0, stream>>>(
        xin, proj_W + (size_t)l * 768 * 768, proj_b + l * 768, h_in,
        768, 768, 768);

    dim3 g2(18, 16);
    gemm_nt<true><<<g2, 256, 0, stream>>>(
        h_in, Wih, bih, gi3, 768, 768, 0);

    gru_kernel<<<96, 512, 0, stream>>>(gi3, h_seq, hstepL, hprevL, Whh, bhh);

    router_kernel<<<2048, 64, 0, stream>>>(h_seq, rW + (size_t)l * 8 * 768,
                                           rb + l * 8, counts + l * 8, lists, gates);

    split_kernel<<<1536, 256, 0, stream>>>(xin, xh, xl, 393216);

    dim3 ga(24, 32, 8);
    gemm_mfma<true, true, false, true><<<ga, 256, 0, stream>>>(
        xh, xl, eW1 + (size_t)l * 8 * 3072 * 768, eb1 + (size_t)l * 8 * 3072,
        nullptr, H1h, H1l, 768, 768, 3072,
        lists, counts + l * 8, nullptr, (long)3072 * 768, 3072);

    dim3 gb(6, 32, 8);
    gemm_mfma<false, false, true, false><<<gb, 256, 0, stream>>>(
        H1h, H1l, eW2 + (size_t)l * 8 * 768 * 3072, eb2 + (size_t)l * 8 * 768,
        ybuf, nullptr, nullptr, 3072, 3072, 768,
        lists, counts + l * 8, gates, (long)768 * 3072, 768);

    combine_kernel<<<1536, 256, 0, stream>>>(ybuf, l ? out : x_buf);
  }
}

// Round 19
// 4926.771 us; speedup vs baseline: 1.0159x; 1.0159x over previous
//
#include <hip/hip_runtime.h>
#include <cmath>

#define AGENT __HIP_MEMORY_SCOPE_AGENT

// Problem constants
// B=4, S=512, I=H=768, 3H=2304, E=8, K=2, L=2, tokens=2048, assignments=4096

typedef __attribute__((ext_vector_type(8))) short short8;
typedef __attribute__((ext_vector_type(4))) float f32x4;

// ---------------- reset: NaN-fill hstep (COHERENT), zero zbuf, counts ----
__global__ __launch_bounds__(256)
void reset_kernel(float* __restrict__ hstep, float* __restrict__ zbuf,
                  int* __restrict__ counts) {
  int i = blockIdx.x * 256 + threadIdx.x;
  if (i < 786432) {   // 2 layers * 512 * 3072 floats / 4
    float qn = __uint_as_float(0x7FC00000u);
    float* p = hstep + (size_t)i * 4;
    __hip_atomic_store(p + 0, qn, __ATOMIC_RELAXED, AGENT);
    __hip_atomic_store(p + 1, qn, __ATOMIC_RELAXED, AGENT);
    __hip_atomic_store(p + 2, qn, __ATOMIC_RELAXED, AGENT);
    __hip_atomic_store(p + 3, qn, __ATOMIC_RELAXED, AGENT);
  }
  if (i < 768) {      // zbuf [4][768] zeros
    float* p = zbuf + (size_t)i * 4;
    __hip_atomic_store(p + 0, 0.f, __ATOMIC_RELAXED, AGENT);
    __hip_atomic_store(p + 1, 0.f, __ATOMIC_RELAXED, AGENT);
    __hip_atomic_store(p + 2, 0.f, __ATOMIC_RELAXED, AGENT);
    __hip_atomic_store(p + 3, 0.f, __ATOMIC_RELAXED, AGENT);
  }
  if (i < 16) counts[i] = 0;
}

// ---------------- split fp32 -> bf16 hi/lo planes (x only, pre-loop) ----
__global__ __launch_bounds__(256)
void split_kernel(const float* __restrict__ in, short* __restrict__ hi,
                  short* __restrict__ lo, int n4) {
  int i = blockIdx.x * 256 + threadIdx.x;
  if (i >= n4) return;
  float4 v = ((const float4*)in)[i];
  unsigned ua = __float_as_uint(v.x), ub = __float_as_uint(v.y);
  unsigned uc = __float_as_uint(v.z), ud = __float_as_uint(v.w);
  unsigned ha = ua & 0xFFFF0000u, hb = ub & 0xFFFF0000u;
  unsigned hc = uc & 0xFFFF0000u, hd = ud & 0xFFFF0000u;
  unsigned hp0 = (ua >> 16) | hb;
  unsigned hp1 = (uc >> 16) | hd;
  float la = v.x - __uint_as_float(ha), lb = v.y - __uint_as_float(hb);
  float lc = v.z - __uint_as_float(hc), ld = v.w - __uint_as_float(hd);
  unsigned lp0 = (__float_as_uint(la) >> 16) | (__float_as_uint(lb) & 0xFFFF0000u);
  unsigned lp1 = (__float_as_uint(lc) >> 16) | (__float_as_uint(ld) & 0xFFFF0000u);
  ((uint2*)hi)[i] = make_uint2(hp0, hp1);
  ((uint2*)lo)[i] = make_uint2(lp0, lp1);
}

// ---------------- dense fp32 GEMM (proj / gi) ----------------
template<bool GI3>
__global__ __launch_bounds__(256)
void gemm_nt(const float* __restrict__ A, const float* __restrict__ Bw,
             const float* __restrict__ bias, float* __restrict__ C,
             int Kd, int lda, int ldc)
{
  __shared__ float As[16][132];
  __shared__ float Bs[16][132];

  int mbase = blockIdx.y * 128;
  int nbase = blockIdx.x * 128;
  int tid = threadIdx.x;
  int tx = tid & 15, ty = tid >> 4;

  const float* ap[2];
  const float* bp[2];
  int ldst[2];
#pragma unroll
  for (int i = 0; i < 2; ++i) {
    int v = tid + 256 * i;
    int row = v >> 2, kq = v & 3;
    ap[i] = A + (size_t)(mbase + row) * lda + kq * 4;
    bp[i] = Bw + (size_t)(nbase + row) * Kd + kq * 4;
    ldst[i] = kq * 4 * 132 + row;
  }

  float acc[8][8];
#pragma unroll
  for (int i = 0; i < 8; ++i)
#pragma unroll
    for (int j = 0; j < 8; ++j) acc[i][j] = 0.f;

  for (int kb = 0; kb < Kd; kb += 16) {
    float4 av[2], bv[2];
#pragma unroll
    for (int i = 0; i < 2; ++i) {
      av[i] = *(const float4*)(ap[i] + kb);
      bv[i] = *(const float4*)(bp[i] + kb);
    }
    if (kb) __syncthreads();
#pragma unroll
    for (int i = 0; i < 2; ++i) {
      float* ad = &As[0][0] + ldst[i];
      ad[0] = av[i].x; ad[132] = av[i].y; ad[264] = av[i].z; ad[396] = av[i].w;
      float* bd = &Bs[0][0] + ldst[i];
      bd[0] = bv[i].x; bd[132] = bv[i].y; bd[264] = bv[i].z; bd[396] = bv[i].w;
    }
    __syncthreads();
#pragma unroll
    for (int kk = 0; kk < 16; ++kk) {
      float a[8], b[8];
      *(float4*)&a[0] = *(const float4*)&As[kk][ty * 4];
      *(float4*)&a[4] = *(const float4*)&As[kk][ty * 4 + 64];
      *(float4*)&b[0] = *(const float4*)&Bs[kk][tx * 4];
      *(float4*)&b[4] = *(const float4*)&Bs[kk][tx * 4 + 64];
#pragma unroll
      for (int i = 0; i < 8; ++i)
#pragma unroll
        for (int j = 0; j < 8; ++j)
          acc[i][j] = fmaf(a[i], b[j], acc[i][j]);
    }
  }

#pragma unroll
  for (int i = 0; i < 8; ++i) {
    int lrow = ty * 4 + (i & 3) + ((i >> 2) << 6);
    int grow = mbase + lrow;
#pragma unroll
    for (int q = 0; q < 2; ++q) {
      int col = nbase + tx * 4 + (q << 6);
      float4 bb = *(const float4*)&bias[col];
      float4 st = make_float4(acc[i][q * 4 + 0] + bb.x, acc[i][q * 4 + 1] + bb.y,
                              acc[i][q * 4 + 2] + bb.z, acc[i][q * 4 + 3] + bb.w);
      if constexpr (GI3) {
        int t = grow & 511, bb2 = grow >> 9;
        int gate = col / 768, jj = col - gate * 768;   // jj%4==0
        int wv = jj >> 2;
        float* dst = C + ((((size_t)t * 4 + bb2) * 192 + wv) * 12 + gate * 4);
        *(float4*)dst = st;
      } else {
        *(float4*)&C[(size_t)grow * ldc + col] = st;
      }
    }
  }
}

// ---------------- split-bf16 MFMA expert GEMM (round-14 proven) ----------
template<bool SHIFT, bool RELU, bool GATE, bool OUTSPLIT>
__global__ __launch_bounds__(256)
void gemm_mfma(const short* __restrict__ Ah_g, const short* __restrict__ Al_g,
               const float* __restrict__ Bw, const float* __restrict__ bias,
               float* __restrict__ C, short* __restrict__ Ch,
               short* __restrict__ Cl, int Kd, int lda, int ldc,
               const int* __restrict__ list, const int* __restrict__ count,
               const float* __restrict__ gates, long wstride, int bstride)
{
  __shared__ __align__(16) short Ah[128][40];
  __shared__ __align__(16) short Al[128][40];
  __shared__ __align__(16) short Bh[128][40];
  __shared__ __align__(16) short Bl[128][40];
  __shared__ int rowlist[128];

  int e = blockIdx.z;
  int cnt = count[e];
  int mbase = blockIdx.y * 128;
  if (mbase >= cnt) return;
  int nbase = blockIdx.x * 128;
  const float* Bp = Bw + (size_t)e * (size_t)wstride;
  const float* biasp = bias + (size_t)e * (size_t)bstride;

  int tid = threadIdx.x;
  if (tid < 128) {
    int r = mbase + tid;
    rowlist[tid] = list[e * 4096 + (r < cnt ? r : cnt - 1)];
  }
  __syncthreads();

  int arow = tid >> 1, ahalf = tid & 1;
  int aidx0 = rowlist[arow];
  int sr = SHIFT ? (aidx0 >> 1) : aidx0;
  const short* aph = Ah_g + (size_t)sr * lda + ahalf * 16;
  const short* apl = Al_g + (size_t)sr * lda + ahalf * 16;
  const float* bp = Bp + (size_t)(nbase + arow) * Kd + ahalf * 16;

  int wave = tid >> 6, lane = tid & 63;
  int wr = (wave >> 1) * 64, wc = (wave & 1) * 64;
  int fr = lane & 15, fo = (lane >> 4) * 8;

  f32x4 acc[4][4];
#pragma unroll
  for (int i = 0; i < 4; ++i)
#pragma unroll
    for (int j = 0; j < 4; ++j) acc[i][j] = f32x4{0.f, 0.f, 0.f, 0.f};

  for (int kb = 0; kb < Kd; kb += 32) {
    uint4 a_h0 = *(const uint4*)(aph + kb);
    uint4 a_h1 = *(const uint4*)(aph + kb + 8);
    uint4 a_l0 = *(const uint4*)(apl + kb);
    uint4 a_l1 = *(const uint4*)(apl + kb + 8);
    float4 b0 = *(const float4*)(bp + kb);
    float4 b1 = *(const float4*)(bp + kb + 4);
    float4 b2 = *(const float4*)(bp + kb + 8);
    float4 b3 = *(const float4*)(bp + kb + 12);
    if (kb) __syncthreads();
    *(uint4*)&Ah[arow][ahalf * 16] = a_h0;
    *(uint4*)&Ah[arow][ahalf * 16 + 8] = a_h1;
    *(uint4*)&Al[arow][ahalf * 16] = a_l0;
    *(uint4*)&Al[arow][ahalf * 16 + 8] = a_l1;
    unsigned hp[8], lp[8];
    const float4 bbv[4] = {b0, b1, b2, b3};
#pragma unroll
    for (int q = 0; q < 4; ++q) {
      unsigned ua = __float_as_uint(bbv[q].x), ub = __float_as_uint(bbv[q].y);
      unsigned uc = __float_as_uint(bbv[q].z), ud = __float_as_uint(bbv[q].w);
      unsigned ha = ua & 0xFFFF0000u, hb = ub & 0xFFFF0000u;
      unsigned hc = uc & 0xFFFF0000u, hd = ud & 0xFFFF0000u;
      hp[q * 2] = (ua >> 16) | hb;
      hp[q * 2 + 1] = (uc >> 16) | hd;
      float la = bbv[q].x - __uint_as_float(ha);
      float lb = bbv[q].y - __uint_as_float(hb);
      float lc = bbv[q].z - __uint_as_float(hc);
      float ld = bbv[q].w - __uint_as_float(hd);
      lp[q * 2] = (__float_as_uint(la) >> 16) | (__float_as_uint(lb) & 0xFFFF0000u);
      lp[q * 2 + 1] = (__float_as_uint(lc) >> 16) | (__float_as_uint(ld) & 0xFFFF0000u);
    }
    *(uint4*)&Bh[arow][ahalf * 16] = make_uint4(hp[0], hp[1], hp[2], hp[3]);
    *(uint4*)&Bh[arow][ahalf * 16 + 8] = make_uint4(hp[4], hp[5], hp[6], hp[7]);
    *(uint4*)&Bl[arow][ahalf * 16] = make_uint4(lp[0], lp[1], lp[2], lp[3]);
    *(uint4*)&Bl[arow][ahalf * 16 + 8] = make_uint4(lp[4], lp[5], lp[6], lp[7]);
    __syncthreads();

    short8 fah[4], fal[4], fbh[4], fbl[4];
#pragma unroll
    for (int mt = 0; mt < 4; ++mt) {
      fah[mt] = *(const short8*)&Ah[wr + mt * 16 + fr][fo];
      fal[mt] = *(const short8*)&Al[wr + mt * 16 + fr][fo];
    }
#pragma unroll
    for (int nt = 0; nt < 4; ++nt) {
      fbh[nt] = *(const short8*)&Bh[wc + nt * 16 + fr][fo];
      fbl[nt] = *(const short8*)&Bl[wc + nt * 16 + fr][fo];
    }
#pragma unroll
    for (int mt = 0; mt < 4; ++mt)
#pragma unroll
      for (int nt = 0; nt < 4; ++nt) {
        acc[mt][nt] = __builtin_amdgcn_mfma_f32_16x16x32_bf16(fah[mt], fbh[nt], acc[mt][nt], 0, 0, 0);
        acc[mt][nt] = __builtin_amdgcn_mfma_f32_16x16x32_bf16(fah[mt], fbl[nt], acc[mt][nt], 0, 0, 0);
        acc[mt][nt] = __builtin_amdgcn_mfma_f32_16x16x32_bf16(fal[mt], fbh[nt], acc[mt][nt], 0, 0, 0);
      }
  }

  int crow = (lane >> 4) * 4;
#pragma unroll
  for (int mt = 0; mt < 4; ++mt) {
#pragma unroll
    for (int q = 0; q < 4; ++q) {
      int lrow = wr + mt * 16 + crow + q;
      int grow = mbase + lrow;
      if (grow < cnt) {
        int aidx = rowlist[lrow];
#pragma unroll
        for (int nt = 0; nt < 4; ++nt) {
          int col = nbase + wc + nt * 16 + fr;
          float v = acc[mt][nt][q] + biasp[col];
          if (RELU) v = fmaxf(v, 0.f);
          if (GATE) v *= gates[aidx];
          if (OUTSPLIT) {
            unsigned u = __float_as_uint(v);
            unsigned h = u & 0xFFFF0000u;
            Ch[(size_t)aidx * ldc + col] = (short)(u >> 16);
            float l2 = v - __uint_as_float(h);
            Cl[(size_t)aidx * ldc + col] = (short)(__float_as_uint(l2) >> 16);
          } else {
            C[(size_t)aidx * ldc + col] = v;
          }
        }
      }
    }
  }
}

// ---------------- GRU persistent kernel (round-17 proven: 1830us) --------
// 4 batch groups x 24 WGs. hstep coherent-only (sc0 sc1) everywhere.
// NaN-sentinel dataflow: producer stores h coherently and proceeds;
// consumers (192 threads) poll their own float4 of hstep[t-1] until
// NaN-free, stage to LDS, compute. One one-way store + one poll sample.
__global__ __launch_bounds__(512, 2)
void gru_kernel(const float* __restrict__ gi3, float* __restrict__ h_seq,
                float* __restrict__ hstep, const float* __restrict__ hprev,
                const float* __restrict__ Whh, const float* __restrict__ bhh)
{
  const int H = 768, S = 512;
  __shared__ float hs[768];
  int wg = blockIdx.x;           // 0..95
  int b = wg / 24;               // batch group 0..3
  int wgi = wg - b * 24;         // 0..23 within group
  int tid = threadIdx.x;         // 0..511
  int wave = tid >> 6;           // 0..7
  int lane = tid & 63;
  int wv = wgi * 8 + wave;       // 0..191: owns cols wv*4..wv*4+3

  float W[4][3][12];
#pragma unroll
  for (int c = 0; c < 4; ++c)
#pragma unroll
    for (int g = 0; g < 3; ++g) {
      const float* wp = Whh + (size_t)(g * H + wv * 4 + c) * H + lane * 4;
      *(float4*)&W[c][g][0] = *(const float4*)(wp);
      *(float4*)&W[c][g][4] = *(const float4*)(wp + 256);
      *(float4*)&W[c][g][8] = *(const float4*)(wp + 512);
    }
  int mycol = wv * 4 + (lane & 3);
  float bh_r = bhh[mycol], bh_z = bhh[H + mycol], bh_n = bhh[2 * H + mycol];

  float h_own = 0.f;
  if (lane < 4)
    h_own = __hip_atomic_load(&hprev[b * H + mycol], __ATOMIC_RELAXED, AGENT);

  for (int tl = 0; tl < S; ++tl) {
    // gi prefetch (plain cached load; latency hidden under the poll)
    float gv = 0.f;
    if (lane < 12)
      gv = gi3[((((size_t)tl * 4 + b) * 192 + wv) * 12) + lane];

    // ---- acquire h[tl-1][b]: per-thread coherent NaN-poll (tid<192) ----
    float4 a = make_float4(0.f, 0.f, 0.f, 0.f);
    if (tid < 192) {   // waves 0..2, wave-uniform
      if (tl == 0) {
        asm volatile("global_load_dwordx4 %0, %1, off sc0 sc1"
                     : "=v"(a) : "v"(hprev + b * 768 + tid * 4) : "memory");
        asm volatile("s_waitcnt vmcnt(0)" ::: "memory");
      } else {
        const float* src = hstep + ((size_t)(tl - 1) * 4 + b) * 768 + tid * 4;
        for (;;) {
          asm volatile("global_load_dwordx4 %0, %1, off sc0 sc1"
                       : "=v"(a) : "v"(src) : "memory");
          asm volatile("s_waitcnt vmcnt(0)" ::: "memory");
          if (!((a.x != a.x) | (a.y != a.y) | (a.z != a.z) | (a.w != a.w)))
            break;
          __builtin_amdgcn_s_sleep(1);
        }
      }
    }
    __builtin_amdgcn_sched_barrier(0);
    if (tid < 192) *(float4*)&hs[tid * 4] = a;
    __syncthreads();

    // ---- sharded h_seq write of h[b][tl-1] (plain store, off chain) ----
    if (tl >= 1 && tid >= wgi * 8 && tid < wgi * 8 + 8)
      *(float4*)&h_seq[((size_t)b * S + (tl - 1)) * H + tid * 4] = a;

    // ---- fragments from LDS ----
    float hseg[12];
    *(float4*)&hseg[0] = *(const float4*)&hs[lane * 4];
    *(float4*)&hseg[4] = *(const float4*)&hs[256 + lane * 4];
    *(float4*)&hseg[8] = *(const float4*)&hs[512 + lane * 4];
    __syncthreads();   // hs safe to overwrite next iteration

    float acc[4][3];
#pragma unroll
    for (int c = 0; c < 4; ++c)
#pragma unroll
      for (int gg = 0; gg < 3; ++gg) {
        float s = 0.f;
#pragma unroll
        for (int i = 0; i < 12; ++i) s = fmaf(W[c][gg][i], hseg[i], s);
        acc[c][gg] = s;
      }
#pragma unroll
    for (int c = 0; c < 4; ++c)
#pragma unroll
      for (int gg = 0; gg < 3; ++gg) {
        float v = acc[c][gg];
#pragma unroll
        for (int m = 32; m >= 1; m >>= 1) v += __shfl_xor(v, m);
        acc[c][gg] = v;
      }

    float gi_r = __shfl(gv, (lane & 3));
    float gi_z = __shfl(gv, 4 + (lane & 3));
    float gi_n = __shfl(gv, 8 + (lane & 3));

    if (lane < 4) {
      float ar = acc[0][0], az = acc[0][1], an = acc[0][2];
      if (lane == 1) { ar = acc[1][0]; az = acc[1][1]; an = acc[1][2]; }
      if (lane == 2) { ar = acc[2][0]; az = acc[2][1]; an = acc[2][2]; }
      if (lane == 3) { ar = acc[3][0]; az = acc[3][1]; an = acc[3][2]; }
      float r = 1.f / (1.f + expf(-(gi_r + ar + bh_r)));
      float z = 1.f / (1.f + expf(-(gi_z + az + bh_z)));
      float n = tanhf(gi_n + r * (an + bh_n));
      float hn = (1.f - z) * n + z * h_own;
      h_own = hn;
      // publish: data is its own tag (single one-way coherent store)
      __hip_atomic_store(&hstep[((size_t)tl * 4 + b) * 768 + mycol], hn,
                         __ATOMIC_RELAXED, AGENT);
    }
  }

  // epilogue: write h[b][S-1] to h_seq from registers
  if (lane < 4)
    h_seq[((size_t)b * S + (S - 1)) * H + mycol] = h_own;
}

// ---------------- router + top-2 + gates + expert lists ----------------
__global__ __launch_bounds__(64)
void router_kernel(const float* __restrict__ h_seq, const float* __restrict__ rW,
                   const float* __restrict__ rb, int* __restrict__ counts,
                   int* __restrict__ lists, float* __restrict__ gates)
{
  int t = blockIdx.x;
  int lane = threadIdx.x;
  const float* hp = h_seq + (size_t)t * 768 + lane * 12;
  float h[12];
  *(float4*)&h[0] = *(const float4*)(hp);
  *(float4*)&h[4] = *(const float4*)(hp + 4);
  *(float4*)&h[8] = *(const float4*)(hp + 8);

  float lg[8];
#pragma unroll
  for (int e = 0; e < 8; ++e) {
    const float* wp = rW + e * 768 + lane * 12;
    float s = 0.f;
#pragma unroll
    for (int i = 0; i < 12; ++i) s = fmaf(h[i], wp[i], s);
#pragma unroll
    for (int m = 32; m >= 1; m >>= 1) s += __shfl_xor(s, m);
    lg[e] = s + rb[e];
  }
  if (lane == 0) {
    float v1 = lg[0]; int e1 = 0;
#pragma unroll
    for (int e = 1; e < 8; ++e) {
      if (lg[e] > v1) { v1 = lg[e]; e1 = e; }
    }
    float v2 = -INFINITY; int es = 0;
#pragma unroll
    for (int e = 0; e < 8; ++e) {
      if (e != e1 && lg[e] > v2) { v2 = lg[e]; es = e; }
    }
    float ed = expf(v2 - v1);
    float g1 = 1.f / (1.f + ed);
    float g2 = ed / (1.f + ed);
    int a0 = t * 2, a1 = t * 2 + 1;
    gates[a0] = g1;
    gates[a1] = g2;
    int p = atomicAdd(&counts[e1], 1);
    lists[e1 * 4096 + p] = a0;
    p = atomicAdd(&counts[es], 1);
    lists[es * 4096 + p] = a1;
  }
}

// ---------------- combine (+fused split): x_next = y0+y1; emit hi/lo ----
__global__ __launch_bounds__(256)
void combine_kernel(const float* __restrict__ ybuf, float* __restrict__ out,
                    short* __restrict__ hi, short* __restrict__ lo)
{
  int i = blockIdx.x * 256 + threadIdx.x;
  int fi = i * 4;
  int t = fi / 768;
  int d = fi % 768;
  float4 y0 = *(const float4*)&ybuf[(size_t)(2 * t) * 768 + d];
  float4 y1 = *(const float4*)&ybuf[(size_t)(2 * t + 1) * 768 + d];
  float4 r = make_float4(y0.x + y1.x, y0.y + y1.y, y0.z + y1.z, y0.w + y1.w);
  *(float4*)&out[fi] = r;
  // fused bf16 hi/lo split (next layer's expert-GEMM A operand)
  unsigned ua = __float_as_uint(r.x), ub = __float_as_uint(r.y);
  unsigned uc = __float_as_uint(r.z), ud = __float_as_uint(r.w);
  unsigned ha = ua & 0xFFFF0000u, hb = ub & 0xFFFF0000u;
  unsigned hc = uc & 0xFFFF0000u, hd = ud & 0xFFFF0000u;
  unsigned hp0 = (ua >> 16) | hb;
  unsigned hp1 = (uc >> 16) | hd;
  float la = r.x - __uint_as_float(ha), lb = r.y - __uint_as_float(hb);
  float lc = r.z - __uint_as_float(hc), ld = r.w - __uint_as_float(hd);
  unsigned lp0 = (__float_as_uint(la) >> 16) | (__float_as_uint(lb) & 0xFFFF0000u);
  unsigned lp1 = (__float_as_uint(lc) >> 16) | (__float_as_uint(ld) & 0xFFFF0000u);
  ((uint2*)hi)[i] = make_uint2(hp0, hp1);
  ((uint2*)lo)[i] = make_uint2(lp0, lp1);
}

// ---------------- host ----------------
extern "C" void kernel_launch(void* const* d_in, const int* in_sizes, int n_in,
                              void* d_out, int out_size, void* d_ws, size_t ws_size,
                              hipStream_t stream) {
  (void)in_sizes; (void)n_in; (void)out_size; (void)ws_size;
  const float* x      = (const float*)d_in[0];
  const float* proj_W = (const float*)d_in[1];
  const float* proj_b = (const float*)d_in[2];
  const float* Wih    = (const float*)d_in[3];
  const float* Whh    = (const float*)d_in[4];
  const float* bih    = (const float*)d_in[5];
  const float* bhh    = (const float*)d_in[6];
  const float* rW     = (const float*)d_in[7];
  const float* rb     = (const float*)d_in[8];
  const float* eW1    = (const float*)d_in[9];
  const float* eb1    = (const float*)d_in[10];
  const float* eW2    = (const float*)d_in[11];
  const float* eb2    = (const float*)d_in[12];
  float* out = (float*)d_out;

  // workspace layout
  float* f = (float*)d_ws;
  float* h_in  = f;                    // 1,572,864
  float* gi3   = h_in + 1572864;       // 512*4*192*12 = 4,718,592
  float* h_seq = gi3 + 4718592;        // 1,572,864
  float* x_buf = h_seq + 1572864;      // 1,572,864
  float* ybuf  = x_buf + 1572864;      // 3,145,728
  float* hstep = ybuf + 3145728;       // 2*512*4*768 = 3,145,728
  float* zbuf  = hstep + 3145728;      // 3,072 ([4][768] zeros)
  float* gates = zbuf + 3072;          // 4,096
  short* xh    = (short*)(gates + 4096);  // 1,572,864 shorts
  short* xl    = xh + 1572864;            // 1,572,864 shorts
  short* H1h   = xl + 1572864;            // 12,582,912 shorts
  short* H1l   = H1h + 12582912;          // 12,582,912 shorts
  int* ints    = (int*)(H1l + 12582912);
  int* counts  = ints;                 // 16
  int* lists   = ints + 16;            // 8*4096

  reset_kernel<<<3072, 256, 0, stream>>>(hstep, zbuf, counts);
  split_kernel<<<1536, 256, 0, stream>>>(x, xh, xl, 393216);   // layer-0 A

  for (int l = 0; l < 2; ++l) {
    const float* xin = l ? x_buf : x;
    float* hstepL = hstep + (size_t)l * 1572864;
    const float* hprevL = l ? (hstep + (size_t)511 * 3072) : zbuf;

    dim3 g1(6, 16);
    gemm_nt<false><<<g1, 256, 0, stream>>>(
        xin, proj_W + (size_t)l * 768 * 768, proj_b + l * 768, h_in,
        768, 768, 768);

    dim3 g2(18, 16);
    gemm_nt<true><<<g2, 256, 0, stream>>>(
        h_in, Wih, bih, gi3, 768, 768, 0);

    gru_kernel<<<96, 512, 0, stream>>>(gi3, h_seq, hstepL, hprevL, Whh, bhh);

    router_kernel<<<2048, 64, 0, stream>>>(h_seq, rW + (size_t)l * 8 * 768,
                                           rb + l * 8, counts + l * 8, lists, gates);

    dim3 ga(24, 32, 8);
    gemm_mfma<true, true, false, true><<<ga, 256, 0, stream>>>(
        xh, xl, eW1 + (size_t)l * 8 * 3072 * 768, eb1 + (size_t)l * 8 * 3072,
        nullptr, H1h, H1l, 768, 768, 3072,
        lists, counts + l * 8, nullptr, (long)3072 * 768, 3072);

    dim3 gb(6, 32, 8);
    gemm_mfma<false, false, true, false><<<gb, 256, 0, stream>>>(
        H1h, H1l, eW2 + (size_t)l * 8 * 768 * 3072, eb2 + (size_t)l * 8 * 768,
        ybuf, nullptr, nullptr, 3072, 3072, 768,
        lists, counts + l * 8, gates, (long)768 * 3072, 768);

    // combine writes x_buf (or final out) AND the next layer's bf16 planes
    combine_kernel<<<1536, 256, 0, stream>>>(ybuf, l ? out : x_buf, xh, xl);
  }
}